// Round 1
// baseline (7804.400 us; speedup 1.0000x reference)
//
#include <hip/hip_runtime.h>
#include <hip/hip_bf16.h>
#include <stdint.h>

typedef __hip_bfloat16 bf16;
typedef __attribute__((ext_vector_type(8))) short short8;
typedef __attribute__((ext_vector_type(4))) float f32x4;

static constexpr int TB = 8;     // batch
static constexpr int TT = 1024;  // seq len
static constexpr int TD = 1024;  // d_model
static constexpr int TH = 16;    // heads
static constexpr int THD = 64;   // head dim
static constexpr int TL = 4;     // layers
static constexpr int TDF = 4096; // ffn dim
static constexpr int TM = TB * TT; // 8192 rows

// ---------------- embedding: x = tok_emb[idx] + pos_emb ----------------
__global__ __launch_bounds__(256) void k_embed(const int* __restrict__ idx,
        const float* __restrict__ tok, const float* __restrict__ pos,
        float* __restrict__ x) {
    int row = blockIdx.x;            // b*T + t
    int t = row & (TT - 1);
    int token = idx[row];
    int c = threadIdx.x * 4;
    float4 tv = *(const float4*)(tok + (int64_t)token * TD + c);
    float4 pv = *(const float4*)(pos + (int64_t)t * TD + c);
    *(float4*)(x + (int64_t)row * TD + c) =
        make_float4(tv.x + pv.x, tv.y + pv.y, tv.z + pv.z, tv.w + pv.w);
}

// ---------------- layernorm: fp32 in -> bf16 out ----------------
__global__ __launch_bounds__(256) void k_ln(const float* __restrict__ x,
        const float* __restrict__ w, const float* __restrict__ b,
        bf16* __restrict__ out) {
    int row = blockIdx.x;
    int tid = threadIdx.x;
    const float* xr = x + (int64_t)row * TD;
    float4 v = *(const float4*)(xr + tid * 4);
    float s  = v.x + v.y + v.z + v.w;
    float s2 = v.x*v.x + v.y*v.y + v.z*v.z + v.w*v.w;
    #pragma unroll
    for (int off = 32; off; off >>= 1) { s += __shfl_xor(s, off); s2 += __shfl_xor(s2, off); }
    __shared__ float red[8];
    int wv_ = tid >> 6, ln_ = tid & 63;
    if (ln_ == 0) { red[wv_] = s; red[4 + wv_] = s2; }
    __syncthreads();
    s  = red[0] + red[1] + red[2] + red[3];
    s2 = red[4] + red[5] + red[6] + red[7];
    float mean = s * (1.f / TD);
    float var  = s2 * (1.f / TD) - mean * mean;
    float rstd = rsqrtf(var + 1e-5f);
    float4 wv4 = *(const float4*)(w + tid * 4);
    float4 bv4 = *(const float4*)(b + tid * 4);
    bf16 t4[4];
    t4[0] = __float2bfloat16((v.x - mean) * rstd * wv4.x + bv4.x);
    t4[1] = __float2bfloat16((v.y - mean) * rstd * wv4.y + bv4.y);
    t4[2] = __float2bfloat16((v.z - mean) * rstd * wv4.z + bv4.z);
    t4[3] = __float2bfloat16((v.w - mean) * rstd * wv4.w + bv4.w);
    *(uint2*)(out + (int64_t)row * TD + tid * 4) = *(uint2*)t4;
}

// ---------------- transpose + fp32->bf16: W[K][N] -> WT[N][K] ----------------
__global__ __launch_bounds__(256) void k_transpose(const float* __restrict__ W,
        bf16* __restrict__ WT, int K, int N) {
    __shared__ bf16 tile[64 * 72];
    int n0 = blockIdx.x * 64, k0 = blockIdx.y * 64;
    int tid = threadIdx.x;
    #pragma unroll
    for (int i = 0; i < 16; i++) {
        int q = i * 256 + tid;          // 0..4095
        int r = q >> 6, c = q & 63;
        tile[r * 72 + c] = __float2bfloat16(W[(int64_t)(k0 + r) * N + n0 + c]);
    }
    __syncthreads();
    #pragma unroll
    for (int i = 0; i < 16; i++) {
        int q = i * 256 + tid;
        int nr = q >> 6, kc = q & 63;
        WT[(int64_t)(n0 + nr) * K + k0 + kc] = tile[kc * 72 + nr];
    }
}

// ---------------- GEMM: C[M,N] = A[M,K](bf16) * BT[N,K](bf16)^T ----------------
// EPI bits: 1=+bias, 2=relu, 4=+residual, 8=fp32 out (else bf16 out)
template<int EPI>
__global__ __launch_bounds__(256) void k_gemm(const bf16* __restrict__ A,
        const bf16* __restrict__ BT, const float* __restrict__ bias,
        const float* __restrict__ resid, float* __restrict__ outF,
        bf16* __restrict__ outB, int M, int N, int K) {
    // LDS tiles: 128 rows x 64 bf16, row stride 144 B (pad breaks bank aliasing)
    __shared__ __align__(16) char As[128 * 144];
    __shared__ __align__(16) char Bs[128 * 144];
    const int tid = threadIdx.x;
    const int lane = tid & 63, wave = tid >> 6;
    const int wm = wave >> 1, wn = wave & 1;     // 2x2 waves, 64x64 each
    const int lr = lane & 15, lk = lane >> 4;
    const int bn = blockIdx.x, bm = blockIdx.y;

    f32x4 acc[4][4] = {};

    const int64_t aBase = (int64_t)bm * 128 * K;
    const int64_t bBase = (int64_t)bn * 128 * K;

    for (int kt = 0; kt < K; kt += 64) {
        __syncthreads();
        #pragma unroll
        for (int i = 0; i < 4; i++) {
            int q = i * 256 + tid;      // 0..1023 chunk id
            int r = q >> 3, c8 = q & 7; // row, 16B-chunk within row
            uint4 av = *(const uint4*)(A + aBase + (int64_t)r * K + kt + c8 * 8);
            *(uint4*)(As + r * 144 + c8 * 16) = av;
            uint4 bv = *(const uint4*)(BT + bBase + (int64_t)r * K + kt + c8 * 8);
            *(uint4*)(Bs + r * 144 + c8 * 16) = bv;
        }
        __syncthreads();
        #pragma unroll
        for (int kk = 0; kk < 2; kk++) {
            const int kbyte = kk * 64 + lk * 16;
            short8 af[4], bf_[4];
            #pragma unroll
            for (int f = 0; f < 4; f++) {
                af[f]  = *(const short8*)(As + (wm * 64 + f * 16 + lr) * 144 + kbyte);
                bf_[f] = *(const short8*)(Bs + (wn * 64 + f * 16 + lr) * 144 + kbyte);
            }
            #pragma unroll
            for (int fm = 0; fm < 4; fm++)
                #pragma unroll
                for (int fn = 0; fn < 4; fn++)
                    acc[fm][fn] = __builtin_amdgcn_mfma_f32_16x16x32_bf16(
                        af[fm], bf_[fn], acc[fm][fn], 0, 0, 0);
        }
    }

    #pragma unroll
    for (int fm = 0; fm < 4; fm++) {
        #pragma unroll
        for (int fn = 0; fn < 4; fn++) {
            const int col = bn * 128 + wn * 64 + fn * 16 + lr;
            #pragma unroll
            for (int r = 0; r < 4; r++) {
                const int row = bm * 128 + wm * 64 + fm * 16 + lk * 4 + r;
                float v = acc[fm][fn][r];
                if constexpr (EPI & 1) v += bias[col];
                if constexpr (EPI & 2) v = fmaxf(v, 0.f);
                if constexpr (EPI & 4) v += resid[(int64_t)row * N + col];
                if constexpr (EPI & 8) outF[(int64_t)row * N + col] = v;
                else outB[(int64_t)row * N + col] = __float2bfloat16(v);
            }
        }
    }
}

// ---------------- flash attention: one wave per (b,h,t) ----------------
__global__ __launch_bounds__(256) void k_attn(const bf16* __restrict__ Q,
        const bf16* __restrict__ Km, const bf16* __restrict__ Vm,
        bf16* __restrict__ O) {
    const int lane = threadIdx.x & 63;
    const int wid = blockIdx.x * 4 + (threadIdx.x >> 6);
    const int t = wid & (TT - 1);
    const int h = (wid >> 10) & (TH - 1);
    const int b = wid >> 14;
    const float scale = 1.0f / 32.0f;  // D^-0.5 (full embed dim, per reference)

    const int64_t qoff = ((int64_t)(b * TT + t)) * TD + h * THD;
    float q[THD];
    #pragma unroll
    for (int d0 = 0; d0 < THD; d0 += 8) {
        uint4 raw = *(const uint4*)(Q + qoff + d0);  // wave-uniform broadcast
        const bf16* p = (const bf16*)&raw;
        #pragma unroll
        for (int i = 0; i < 8; i++) q[d0 + i] = __bfloat162float(p[i]) * scale;
    }
    float m = -INFINITY, l = 0.f, acc = 0.f;
    const int64_t base = (int64_t)b * TT * TD + h * THD;
    for (int s0 = 0; s0 <= t; s0 += 64) {
        // lane j scores key s0+j
        float dot = 0.f;
        const int64_t rowk = base + (int64_t)(s0 + lane) * TD;
        #pragma unroll
        for (int d0 = 0; d0 < THD; d0 += 8) {
            uint4 raw = *(const uint4*)(Km + rowk + d0);
            const bf16* p = (const bf16*)&raw;
            #pragma unroll
            for (int i = 0; i < 8; i++) dot = fmaf(q[d0 + i], __bfloat162float(p[i]), dot);
        }
        float score = (s0 + lane <= t) ? dot : -INFINITY;
        float mx = score;
        #pragma unroll
        for (int off = 32; off; off >>= 1) mx = fmaxf(mx, __shfl_xor(mx, off));
        const float m_new = fmaxf(m, mx);
        const float p = __expf(score - m_new);   // exp(-inf)=0 masks future keys
        float ps = p;
        #pragma unroll
        for (int off = 32; off; off >>= 1) ps += __shfl_xor(ps, off);
        const float c = __expf(m - m_new);
        l = l * c + ps;
        acc *= c;
        // PV: lane = output dim d, broadcast p_j; V reads coalesced
        const int64_t vcol = base + (int64_t)s0 * TD + lane;
        #pragma unroll 8
        for (int jj = 0; jj < 64; jj++) {
            float pj = __shfl(p, jj);
            acc = fmaf(pj, __bfloat162float(Vm[vcol + (int64_t)jj * TD]), acc);
        }
        m = m_new;
    }
    O[qoff + lane] = __float2bfloat16(acc / l);
}

extern "C" void kernel_launch(void* const* d_in, const int* in_sizes, int n_in,
                              void* d_out, int out_size, void* d_ws, size_t ws_size,
                              hipStream_t stream) {
    const int*   idx  = (const int*)  d_in[0];
    const float* tok  = (const float*)d_in[1];
    const float* pos  = (const float*)d_in[2];
    const float* wq   = (const float*)d_in[3];
    const float* wk   = (const float*)d_in[4];
    const float* wv   = (const float*)d_in[5];
    const float* wp   = (const float*)d_in[6];
    const float* bp   = (const float*)d_in[7];
    const float* ln1w = (const float*)d_in[8];
    const float* ln1b = (const float*)d_in[9];
    const float* ln2w = (const float*)d_in[10];
    const float* ln2b = (const float*)d_in[11];
    const float* w1   = (const float*)d_in[12];
    const float* b1   = (const float*)d_in[13];
    const float* w2   = (const float*)d_in[14];
    const float* b2   = (const float*)d_in[15];
    float* x = (float*)d_out;   // residual stream lives in d_out (fp32)

    char* ws = (char*)d_ws;
    size_t off = 0;
    auto alloc = [&](size_t bytes) {
        char* p = ws + off; off += (bytes + 255) & ~(size_t)255; return p;
    };
    bf16* h   = (bf16*)alloc((size_t)TM * TD * 2);
    bf16* qb  = (bf16*)alloc((size_t)TM * TD * 2);
    bf16* kb  = (bf16*)alloc((size_t)TM * TD * 2);
    bf16* vb  = (bf16*)alloc((size_t)TM * TD * 2);
    bf16* ctx = (bf16*)alloc((size_t)TM * TD * 2);
    bf16* ffa = (bf16*)alloc((size_t)TM * TDF * 2);
    bf16* wqT = (bf16*)alloc((size_t)TD * TD * 2);
    bf16* wkT = (bf16*)alloc((size_t)TD * TD * 2);
    bf16* wvT = (bf16*)alloc((size_t)TD * TD * 2);
    bf16* wpT = (bf16*)alloc((size_t)TD * TD * 2);
    bf16* w1T = (bf16*)alloc((size_t)TD * TDF * 2);
    bf16* w2T = (bf16*)alloc((size_t)TD * TDF * 2);

    k_embed<<<TM, 256, 0, stream>>>(idx, tok, pos, x);

    const dim3 gD(TD / 128, TM / 128);    // (8, 64)
    const dim3 gF1(TDF / 128, TM / 128);  // (32, 64)

    for (int l = 0; l < TL; l++) {
        k_transpose<<<dim3(TD / 64, TD / 64), 256, 0, stream>>>(wq + (int64_t)l * TD * TD, wqT, TD, TD);
        k_transpose<<<dim3(TD / 64, TD / 64), 256, 0, stream>>>(wk + (int64_t)l * TD * TD, wkT, TD, TD);
        k_transpose<<<dim3(TD / 64, TD / 64), 256, 0, stream>>>(wv + (int64_t)l * TD * TD, wvT, TD, TD);
        k_transpose<<<dim3(TD / 64, TD / 64), 256, 0, stream>>>(wp + (int64_t)l * TD * TD, wpT, TD, TD);
        k_transpose<<<dim3(TDF / 64, TD / 64), 256, 0, stream>>>(w1 + (int64_t)l * TD * TDF, w1T, TD, TDF);
        k_transpose<<<dim3(TD / 64, TDF / 64), 256, 0, stream>>>(w2 + (int64_t)l * TDF * TD, w2T, TDF, TD);

        k_ln<<<TM, 256, 0, stream>>>(x, ln1w + l * TD, ln1b + l * TD, h);
        k_gemm<0><<<gD, 256, 0, stream>>>(h, wqT, nullptr, nullptr, nullptr, qb, TM, TD, TD);
        k_gemm<0><<<gD, 256, 0, stream>>>(h, wkT, nullptr, nullptr, nullptr, kb, TM, TD, TD);
        k_gemm<0><<<gD, 256, 0, stream>>>(h, wvT, nullptr, nullptr, nullptr, vb, TM, TD, TD);
        k_attn<<<TB * TH * TT / 4, 256, 0, stream>>>(qb, kb, vb, ctx);
        k_gemm<13><<<gD, 256, 0, stream>>>(ctx, wpT, bp + l * TD, x, x, nullptr, TM, TD, TD);
        k_ln<<<TM, 256, 0, stream>>>(x, ln2w + l * TD, ln2b + l * TD, h);
        k_gemm<3><<<gF1, 256, 0, stream>>>(h, w1T, b1 + l * TDF, nullptr, nullptr, ffa, TM, TDF, TD);
        k_gemm<13><<<gD, 256, 0, stream>>>(ffa, w2T, b2 + l * TD, x, x, nullptr, TM, TD, TDF);
    }
    (void)in_sizes; (void)n_in; (void)out_size; (void)ws_size;
}

// Round 3
// 2144.339 us; speedup vs baseline: 3.6395x; 3.6395x over previous
//
#include <hip/hip_runtime.h>
#include <hip/hip_bf16.h>
#include <stdint.h>

typedef __hip_bfloat16 bf16;
typedef __attribute__((ext_vector_type(8))) short short8;
typedef __attribute__((ext_vector_type(4))) float f32x4;

static constexpr int TB = 8;     // batch
static constexpr int TT = 1024;  // seq len
static constexpr int TD = 1024;  // d_model
static constexpr int TH = 16;    // heads
static constexpr int THD = 64;   // head dim
static constexpr int TL = 4;     // layers
static constexpr int TDF = 4096; // ffn dim
static constexpr int TM = TB * TT; // 8192 rows

// ---------------- embedding: x = tok_emb[idx] + pos_emb ----------------
__global__ __launch_bounds__(256) void k_embed(const int* __restrict__ idx,
        const float* __restrict__ tok, const float* __restrict__ pos,
        float* __restrict__ x) {
    int row = blockIdx.x;            // b*T + t
    int t = row & (TT - 1);
    int token = idx[row];
    int c = threadIdx.x * 4;
    float4 tv = *(const float4*)(tok + (int64_t)token * TD + c);
    float4 pv = *(const float4*)(pos + (int64_t)t * TD + c);
    *(float4*)(x + (int64_t)row * TD + c) =
        make_float4(tv.x + pv.x, tv.y + pv.y, tv.z + pv.z, tv.w + pv.w);
}

// ---------------- layernorm: fp32 in -> bf16 out ----------------
__global__ __launch_bounds__(256) void k_ln(const float* __restrict__ x,
        const float* __restrict__ w, const float* __restrict__ b,
        bf16* __restrict__ out) {
    int row = blockIdx.x;
    int tid = threadIdx.x;
    const float* xr = x + (int64_t)row * TD;
    float4 v = *(const float4*)(xr + tid * 4);
    float s  = v.x + v.y + v.z + v.w;
    float s2 = v.x*v.x + v.y*v.y + v.z*v.z + v.w*v.w;
    #pragma unroll
    for (int off = 32; off; off >>= 1) { s += __shfl_xor(s, off); s2 += __shfl_xor(s2, off); }
    __shared__ float red[8];
    int wv_ = tid >> 6, ln_ = tid & 63;
    if (ln_ == 0) { red[wv_] = s; red[4 + wv_] = s2; }
    __syncthreads();
    s  = red[0] + red[1] + red[2] + red[3];
    s2 = red[4] + red[5] + red[6] + red[7];
    float mean = s * (1.f / TD);
    float var  = s2 * (1.f / TD) - mean * mean;
    float rstd = rsqrtf(var + 1e-5f);
    float4 wv4 = *(const float4*)(w + tid * 4);
    float4 bv4 = *(const float4*)(b + tid * 4);
    bf16 t4[4];
    t4[0] = __float2bfloat16((v.x - mean) * rstd * wv4.x + bv4.x);
    t4[1] = __float2bfloat16((v.y - mean) * rstd * wv4.y + bv4.y);
    t4[2] = __float2bfloat16((v.z - mean) * rstd * wv4.z + bv4.z);
    t4[3] = __float2bfloat16((v.w - mean) * rstd * wv4.w + bv4.w);
    *(uint2*)(out + (int64_t)row * TD + tid * 4) = *(uint2*)t4;
}

// ---------------- transpose + fp32->bf16: W[K][N] -> WT[N][K] ----------------
__global__ __launch_bounds__(256) void k_transpose(const float* __restrict__ W,
        bf16* __restrict__ WT, int K, int N) {
    __shared__ bf16 tile[64 * 74];
    int n0 = blockIdx.x * 64, k0 = blockIdx.y * 64;
    int tid = threadIdx.x;
    #pragma unroll
    for (int i = 0; i < 16; i++) {
        int q = i * 256 + tid;          // 0..4095
        int r = q >> 6, c = q & 63;
        tile[r * 74 + c] = __float2bfloat16(W[(int64_t)(k0 + r) * N + n0 + c]);
    }
    __syncthreads();
    #pragma unroll
    for (int i = 0; i < 16; i++) {
        int q = i * 256 + tid;
        int nr = q >> 6, kc = q & 63;
        WT[(int64_t)(n0 + nr) * K + k0 + kc] = tile[kc * 74 + nr];
    }
}

// ---------------- V transpose: vb[B*T][D] -> vt[b][h][64 dims][1024 keys] ----
__global__ __launch_bounds__(256) void k_vt(const bf16* __restrict__ vb,
        bf16* __restrict__ vt) {
    __shared__ bf16 tile[64 * 74];
    const int bh = blockIdx.x;            // b*16+h
    const int b = bh >> 4, h = bh & 15;
    const int t0 = blockIdx.y * 64;
    const int tid = threadIdx.x;
    #pragma unroll
    for (int i = 0; i < 16; i++) {
        int q = i * 256 + tid;
        int r = q >> 6, c = q & 63;       // r = t offset, c = dim
        tile[r * 74 + c] = vb[(int64_t)(b * TT + t0 + r) * TD + h * 64 + c];
    }
    __syncthreads();
    #pragma unroll
    for (int i = 0; i < 16; i++) {
        int q = i * 256 + tid;
        int d = q >> 6, tc = q & 63;      // d = dim row, tc = t offset
        vt[((int64_t)bh * 64 + d) * TT + t0 + tc] = tile[tc * 74 + d];
    }
}

// ---------------- GEMM: C[M,N] = A[M,K](bf16) * BT[N,K](bf16)^T ----------------
// EPI bits: 1=+bias, 2=relu, 4=+residual, 8=fp32 out (else bf16 out)
template<int EPI>
__global__ __launch_bounds__(256) void k_gemm(const bf16* __restrict__ A,
        const bf16* __restrict__ BT, const float* __restrict__ bias,
        const float* __restrict__ resid, float* __restrict__ outF,
        bf16* __restrict__ outB, int M, int N, int K) {
    __shared__ __align__(16) char As[128 * 144];
    __shared__ __align__(16) char Bs[128 * 144];
    const int tid = threadIdx.x;
    const int lane = tid & 63, wave = tid >> 6;
    const int wm = wave >> 1, wn = wave & 1;     // 2x2 waves, 64x64 each
    const int lr = lane & 15, lk = lane >> 4;
    const int bn = blockIdx.x, bm = blockIdx.y;

    f32x4 acc[4][4] = {};

    const int64_t aBase = (int64_t)bm * 128 * K;
    const int64_t bBase = (int64_t)bn * 128 * K;

    for (int kt = 0; kt < K; kt += 64) {
        __syncthreads();
        #pragma unroll
        for (int i = 0; i < 4; i++) {
            int q = i * 256 + tid;      // 0..1023 chunk id
            int r = q >> 3, c8 = q & 7; // row, 16B-chunk within row
            uint4 av = *(const uint4*)(A + aBase + (int64_t)r * K + kt + c8 * 8);
            *(uint4*)(As + r * 144 + c8 * 16) = av;
            uint4 bv = *(const uint4*)(BT + bBase + (int64_t)r * K + kt + c8 * 8);
            *(uint4*)(Bs + r * 144 + c8 * 16) = bv;
        }
        __syncthreads();
        #pragma unroll
        for (int kk = 0; kk < 2; kk++) {
            const int kbyte = kk * 64 + lk * 16;
            short8 af[4], bf_[4];
            #pragma unroll
            for (int f = 0; f < 4; f++) {
                af[f]  = *(const short8*)(As + (wm * 64 + f * 16 + lr) * 144 + kbyte);
                bf_[f] = *(const short8*)(Bs + (wn * 64 + f * 16 + lr) * 144 + kbyte);
            }
            #pragma unroll
            for (int fm = 0; fm < 4; fm++)
                #pragma unroll
                for (int fn = 0; fn < 4; fn++)
                    acc[fm][fn] = __builtin_amdgcn_mfma_f32_16x16x32_bf16(
                        af[fm], bf_[fn], acc[fm][fn], 0, 0, 0);
        }
    }

    #pragma unroll
    for (int fm = 0; fm < 4; fm++) {
        #pragma unroll
        for (int fn = 0; fn < 4; fn++) {
            const int col = bn * 128 + wn * 64 + fn * 16 + lr;
            #pragma unroll
            for (int r = 0; r < 4; r++) {
                const int row = bm * 128 + wm * 64 + fm * 16 + lk * 4 + r;
                float v = acc[fm][fn][r];
                if constexpr (EPI & 1) v += bias[col];
                if constexpr (EPI & 2) v = fmaxf(v, 0.f);
                if constexpr (EPI & 4) v += resid[(int64_t)row * N + col];
                if constexpr (EPI & 8) outF[(int64_t)row * N + col] = v;
                else outB[(int64_t)row * N + col] = __float2bfloat16(v);
            }
        }
    }
}

// ---------------- MFMA flash attention ----------------
// One wave per 16-query tile. S^T = mfma(K,Q): col=query(lane&15), row=key.
// ctx^T = mfma(V^T, P^T): col=query, row=dim. m/l state lane-local per query.
__global__ __launch_bounds__(256) void k_attn2(const bf16* __restrict__ Q,
        const bf16* __restrict__ Kb, const bf16* __restrict__ Vt,
        bf16* __restrict__ O) {
    const int lane = threadIdx.x & 63;
    const int wave = threadIdx.x >> 6;
    int bid = (blockIdx.x & 7) * 256 + (blockIdx.x >> 3);  // XCD-contiguous, bijective on 2048
    const int wid = bid * 4 + wave;                        // 0..8191
    const int qt = wid & 63, h = (wid >> 6) & 15, b = wid >> 10;
    const int q0 = qt * 16;
    const int c = lane & 15, g = lane >> 4;
    const int qg = q0 + c;                 // this lane's query (output col)
    const float scale = 1.0f / 32.0f;      // D^-0.5 (full embed dim, per ref)

    // Q B-frag: col=query=c, k-elems hd = g*8+{0..7} (+32 per tile)
    const bf16* qrow = Q + ((int64_t)(b * TT + q0 + c)) * TD + h * 64 + g * 8;
    short8 qf0 = *(const short8*)(qrow);
    short8 qf1 = *(const short8*)(qrow + 32);

    f32x4 ctx[4] = {};                     // dim-tiles: col=query, row=dim 4g+r
    float mrun = -INFINITY, lrun = 0.f;

    const bf16* kbase = Kb + ((int64_t)b * TT) * TD + h * 64;
    const bf16* vbase = Vt + ((int64_t)(b * TH + h) * 64) * TT;

    const int nk = q0 + 16;                // need keys 0..q0+15
    for (int k0 = 0; k0 < nk; k0 += 32) {
        // ---- QK^T (swapped): S^T tiles, keys k0+16j+(4g+r) ----
        const bf16* kp = kbase + (int64_t)(k0 + c) * TD + g * 8;
        short8 kf00 = *(const short8*)(kp);
        short8 kf01 = *(const short8*)(kp + 32);
        f32x4 st0 = {}, st1 = {};
        st0 = __builtin_amdgcn_mfma_f32_16x16x32_bf16(kf00, qf0, st0, 0, 0, 0);
        st0 = __builtin_amdgcn_mfma_f32_16x16x32_bf16(kf01, qf1, st0, 0, 0, 0);
        const bool have2 = (k0 + 16 < nk);
        if (have2) {
            const bf16* kp1 = kp + 16 * TD;
            short8 kf10 = *(const short8*)(kp1);
            short8 kf11 = *(const short8*)(kp1 + 32);
            st1 = __builtin_amdgcn_mfma_f32_16x16x32_bf16(kf10, qf0, st1, 0, 0, 0);
            st1 = __builtin_amdgcn_mfma_f32_16x16x32_bf16(kf11, qf1, st1, 0, 0, 0);
        }
        // ---- online softmax (per query col, lane-local state) ----
        float sv[8];
        #pragma unroll
        for (int r = 0; r < 4; r++) {
            int kg = k0 + 4 * g + r;
            sv[r] = (kg <= qg) ? st0[r] * scale : -INFINITY;
        }
        #pragma unroll
        for (int r = 0; r < 4; r++) {
            int kg = k0 + 16 + 4 * g + r;
            sv[4 + r] = (have2 && kg <= qg) ? st1[r] * scale : -INFINITY;
        }
        float bm = sv[0];
        #pragma unroll
        for (int i = 1; i < 8; i++) bm = fmaxf(bm, sv[i]);
        bm = fmaxf(bm, __shfl_xor(bm, 16));
        bm = fmaxf(bm, __shfl_xor(bm, 32));
        const float mnew = fmaxf(mrun, bm);
        float p[8], psum = 0.f;
        #pragma unroll
        for (int i = 0; i < 8; i++) { p[i] = __expf(sv[i] - mnew); psum += p[i]; }
        psum += __shfl_xor(psum, 16);
        psum += __shfl_xor(psum, 32);
        const float facc = __expf(mrun - mnew);   // 0 on first block (ctx=0)
        lrun = lrun * facc + psum;
        mrun = mnew;
        #pragma unroll
        for (int dt = 0; dt < 4; dt++) ctx[dt] *= facc;

        // ---- pack P^T to bf16 B-frag: lane needs keys 8g+{0..7} of this block ----
        auto pk = [](float a, float b2) -> uint32_t {
            uint16_t lo = __hip_bfloat16_raw(__float2bfloat16(a)).x;
            uint16_t hi = __hip_bfloat16_raw(__float2bfloat16(b2)).x;
            return (uint32_t)lo | ((uint32_t)hi << 16);
        };
        uint32_t w00 = pk(p[0], p[1]), w01 = pk(p[2], p[3]);   // tile0 keys 4g+{0..3}
        uint32_t w10 = pk(p[4], p[5]), w11 = pk(p[6], p[7]);   // tile1
        const int srcA = c + ((g & 1) << 5);      // lane c + 16*(2*(g&1))
        const int srcB = srcA + 16;
        uint32_t x0 = (uint32_t)__shfl((int)w00, srcA);
        uint32_t x1 = (uint32_t)__shfl((int)w01, srcA);
        uint32_t x2 = (uint32_t)__shfl((int)w00, srcB);
        uint32_t x3 = (uint32_t)__shfl((int)w01, srcB);
        uint32_t y0 = (uint32_t)__shfl((int)w10, srcA);
        uint32_t y1 = (uint32_t)__shfl((int)w11, srcA);
        uint32_t y2 = (uint32_t)__shfl((int)w10, srcB);
        uint32_t y3 = (uint32_t)__shfl((int)w11, srcB);
        union { uint32_t u[4]; short8 v; } pa;
        const bool hi2 = (g >= 2);
        pa.u[0] = hi2 ? y0 : x0; pa.u[1] = hi2 ? y1 : x1;
        pa.u[2] = hi2 ? y2 : x2; pa.u[3] = hi2 ? y3 : x3;

        // ---- PV: ctx^T += V^T * P^T ----
        #pragma unroll
        for (int dt = 0; dt < 4; dt++) {
            const bf16* vp = vbase + (int64_t)(dt * 16 + c) * TT + k0 + g * 8;
            short8 vf = *(const short8*)(vp);
            ctx[dt] = __builtin_amdgcn_mfma_f32_16x16x32_bf16(vf, pa.v, ctx[dt], 0, 0, 0);
        }
    }

    // ---- epilogue: O[token q0+c][h*64 + dim], dim = dt*16 + 4g + r ----
    const float inv = 1.0f / lrun;
    bf16* orow = O + ((int64_t)(b * TT + q0 + c)) * TD + h * 64 + g * 4;
    #pragma unroll
    for (int dt = 0; dt < 4; dt++) {
        bf16 t4[4];
        #pragma unroll
        for (int r = 0; r < 4; r++) t4[r] = __float2bfloat16(ctx[dt][r] * inv);
        *(uint2*)(orow + dt * 16) = *(uint2*)t4;
    }
}

extern "C" void kernel_launch(void* const* d_in, const int* in_sizes, int n_in,
                              void* d_out, int out_size, void* d_ws, size_t ws_size,
                              hipStream_t stream) {
    const int*   idx  = (const int*)  d_in[0];
    const float* tok  = (const float*)d_in[1];
    const float* pos  = (const float*)d_in[2];
    const float* wq   = (const float*)d_in[3];
    const float* wk   = (const float*)d_in[4];
    const float* wv   = (const float*)d_in[5];
    const float* wp   = (const float*)d_in[6];
    const float* bp   = (const float*)d_in[7];
    const float* ln1w = (const float*)d_in[8];
    const float* ln1b = (const float*)d_in[9];
    const float* ln2w = (const float*)d_in[10];
    const float* ln2b = (const float*)d_in[11];
    const float* w1   = (const float*)d_in[12];
    const float* b1   = (const float*)d_in[13];
    const float* w2   = (const float*)d_in[14];
    const float* b2   = (const float*)d_in[15];
    float* x = (float*)d_out;   // residual stream lives in d_out (fp32)

    char* ws = (char*)d_ws;
    size_t off = 0;
    auto alloc = [&](size_t bytes) {
        char* p = ws + off; off += (bytes + 255) & ~(size_t)255; return p;
    };
    bf16* h   = (bf16*)alloc((size_t)TM * TD * 2);
    bf16* qb  = (bf16*)alloc((size_t)TM * TD * 2);
    bf16* kb  = (bf16*)alloc((size_t)TM * TD * 2);
    bf16* vb  = (bf16*)alloc((size_t)TM * TD * 2);
    bf16* ctx = (bf16*)alloc((size_t)TM * TD * 2);
    bf16* ffa = (bf16*)alloc((size_t)TM * TDF * 2);
    bf16* wqT = (bf16*)alloc((size_t)TD * TD * 2);
    bf16* wkT = (bf16*)alloc((size_t)TD * TD * 2);
    bf16* wvT = (bf16*)alloc((size_t)TD * TD * 2);
    bf16* wpT = (bf16*)alloc((size_t)TD * TD * 2);
    bf16* w1T = (bf16*)alloc((size_t)TD * TDF * 2);
    bf16* w2T = (bf16*)alloc((size_t)TD * TDF * 2);
    bf16* vt  = (bf16*)ffa;   // reuse: ffa is dead during attention

    k_embed<<<TM, 256, 0, stream>>>(idx, tok, pos, x);

    const dim3 gD(TD / 128, TM / 128);    // (8, 64)
    const dim3 gF1(TDF / 128, TM / 128);  // (32, 64)

    for (int l = 0; l < TL; l++) {
        k_transpose<<<dim3(TD / 64, TD / 64), 256, 0, stream>>>(wq + (int64_t)l * TD * TD, wqT, TD, TD);
        k_transpose<<<dim3(TD / 64, TD / 64), 256, 0, stream>>>(wk + (int64_t)l * TD * TD, wkT, TD, TD);
        k_transpose<<<dim3(TD / 64, TD / 64), 256, 0, stream>>>(wv + (int64_t)l * TD * TD, wvT, TD, TD);
        k_transpose<<<dim3(TD / 64, TD / 64), 256, 0, stream>>>(wp + (int64_t)l * TD * TD, wpT, TD, TD);
        k_transpose<<<dim3(TDF / 64, TD / 64), 256, 0, stream>>>(w1 + (int64_t)l * TD * TDF, w1T, TD, TDF);
        k_transpose<<<dim3(TD / 64, TDF / 64), 256, 0, stream>>>(w2 + (int64_t)l * TDF * TD, w2T, TDF, TD);

        k_ln<<<TM, 256, 0, stream>>>(x, ln1w + l * TD, ln1b + l * TD, h);
        k_gemm<0><<<gD, 256, 0, stream>>>(h, wqT, nullptr, nullptr, nullptr, qb, TM, TD, TD);
        k_gemm<0><<<gD, 256, 0, stream>>>(h, wkT, nullptr, nullptr, nullptr, kb, TM, TD, TD);
        k_gemm<0><<<gD, 256, 0, stream>>>(h, wvT, nullptr, nullptr, nullptr, vb, TM, TD, TD);
        k_vt<<<dim3(TB * TH, TT / 64), 256, 0, stream>>>(vb, vt);
        k_attn2<<<TB * TH * (TT / 16) / 4, 256, 0, stream>>>(qb, kb, vt, ctx);
        k_gemm<13><<<gD, 256, 0, stream>>>(ctx, wpT, bp + l * TD, x, x, nullptr, TM, TD, TD);
        k_ln<<<TM, 256, 0, stream>>>(x, ln2w + l * TD, ln2b + l * TD, h);
        k_gemm<3><<<gF1, 256, 0, stream>>>(h, w1T, b1 + l * TDF, nullptr, nullptr, ffa, TM, TDF, TD);
        k_gemm<13><<<gD, 256, 0, stream>>>(ffa, w2T, b2 + l * TD, x, x, nullptr, TM, TD, TDF);
    }
    (void)in_sizes; (void)n_in; (void)out_size; (void)ws_size;
}

// Round 4
// 1967.973 us; speedup vs baseline: 3.9657x; 1.0896x over previous
//
#include <hip/hip_runtime.h>
#include <hip/hip_bf16.h>
#include <stdint.h>

typedef __hip_bfloat16 bf16;
typedef __attribute__((ext_vector_type(8))) short short8;
typedef __attribute__((ext_vector_type(4))) float f32x4;

static constexpr int TB = 8;     // batch
static constexpr int TT = 1024;  // seq len
static constexpr int TD = 1024;  // d_model
static constexpr int TH = 16;    // heads
static constexpr int THD = 64;   // head dim
static constexpr int TL = 4;     // layers
static constexpr int TDF = 4096; // ffn dim
static constexpr int TM = TB * TT; // 8192 rows

#define GLOAD16(g, l) __builtin_amdgcn_global_load_lds( \
    (const __attribute__((address_space(1))) unsigned int*)(g), \
    (__attribute__((address_space(3))) unsigned int*)(l), 16, 0, 0)

// ---------------- embedding: x = tok_emb[idx] + pos_emb ----------------
__global__ __launch_bounds__(256) void k_embed(const int* __restrict__ idx,
        const float* __restrict__ tok, const float* __restrict__ pos,
        float* __restrict__ x) {
    int row = blockIdx.x;            // b*T + t
    int t = row & (TT - 1);
    int token = idx[row];
    int c = threadIdx.x * 4;
    float4 tv = *(const float4*)(tok + (int64_t)token * TD + c);
    float4 pv = *(const float4*)(pos + (int64_t)t * TD + c);
    *(float4*)(x + (int64_t)row * TD + c) =
        make_float4(tv.x + pv.x, tv.y + pv.y, tv.z + pv.z, tv.w + pv.w);
}

// ---------------- layernorm: fp32 in -> bf16 out ----------------
__global__ __launch_bounds__(256) void k_ln(const float* __restrict__ x,
        const float* __restrict__ w, const float* __restrict__ b,
        bf16* __restrict__ out) {
    int row = blockIdx.x;
    int tid = threadIdx.x;
    const float* xr = x + (int64_t)row * TD;
    float4 v = *(const float4*)(xr + tid * 4);
    float s  = v.x + v.y + v.z + v.w;
    float s2 = v.x*v.x + v.y*v.y + v.z*v.z + v.w*v.w;
    #pragma unroll
    for (int off = 32; off; off >>= 1) { s += __shfl_xor(s, off); s2 += __shfl_xor(s2, off); }
    __shared__ float red[8];
    int wv_ = tid >> 6, ln_ = tid & 63;
    if (ln_ == 0) { red[wv_] = s; red[4 + wv_] = s2; }
    __syncthreads();
    s  = red[0] + red[1] + red[2] + red[3];
    s2 = red[4] + red[5] + red[6] + red[7];
    float mean = s * (1.f / TD);
    float var  = s2 * (1.f / TD) - mean * mean;
    float rstd = rsqrtf(var + 1e-5f);
    float4 wv4 = *(const float4*)(w + tid * 4);
    float4 bv4 = *(const float4*)(b + tid * 4);
    bf16 t4[4];
    t4[0] = __float2bfloat16((v.x - mean) * rstd * wv4.x + bv4.x);
    t4[1] = __float2bfloat16((v.y - mean) * rstd * wv4.y + bv4.y);
    t4[2] = __float2bfloat16((v.z - mean) * rstd * wv4.z + bv4.z);
    t4[3] = __float2bfloat16((v.w - mean) * rstd * wv4.w + bv4.w);
    *(uint2*)(out + (int64_t)row * TD + tid * 4) = *(uint2*)t4;
}

// ---------------- transpose + fp32->bf16: W[K][N] -> WT[N][K] ----------------
__global__ __launch_bounds__(256) void k_transpose(const float* __restrict__ W,
        bf16* __restrict__ WT, int K, int N) {
    __shared__ bf16 tile[64 * 74];
    int n0 = blockIdx.x * 64, k0 = blockIdx.y * 64;
    int tid = threadIdx.x;
    #pragma unroll
    for (int i = 0; i < 16; i++) {
        int q = i * 256 + tid;          // 0..4095
        int r = q >> 6, c = q & 63;
        tile[r * 74 + c] = __float2bfloat16(W[(int64_t)(k0 + r) * N + n0 + c]);
    }
    __syncthreads();
    #pragma unroll
    for (int i = 0; i < 16; i++) {
        int q = i * 256 + tid;
        int nr = q >> 6, kc = q & 63;
        WT[(int64_t)(n0 + nr) * K + k0 + kc] = tile[kc * 74 + nr];
    }
}

// ---------------- V transpose: vb[B*T][D] -> vt[b][h][64 dims][1024 keys] ----
__global__ __launch_bounds__(256) void k_vt(const bf16* __restrict__ vb,
        bf16* __restrict__ vt) {
    __shared__ bf16 tile[64 * 74];
    const int bh = blockIdx.x;            // b*16+h
    const int b = bh >> 4, h = bh & 15;
    const int t0 = blockIdx.y * 64;
    const int tid = threadIdx.x;
    #pragma unroll
    for (int i = 0; i < 16; i++) {
        int q = i * 256 + tid;
        int r = q >> 6, c = q & 63;       // r = t offset, c = dim
        tile[r * 74 + c] = vb[(int64_t)(b * TT + t0 + r) * TD + h * 64 + c];
    }
    __syncthreads();
    #pragma unroll
    for (int i = 0; i < 16; i++) {
        int q = i * 256 + tid;
        int d = q >> 6, tc = q & 63;      // d = dim row, tc = t offset
        vt[((int64_t)bh * 64 + d) * TT + t0 + tc] = tile[tc * 74 + d];
    }
}

// ---------------- GEMM: C[M,N] = A[M,K](bf16) * BT[N,K](bf16)^T ----------------
// m97 structure: linear LDS [128][64], global_load_lds width-16 staging.
// EPI bits: 1=+bias, 2=relu, 4=+residual, 8=fp32 out (else bf16 out)
template<int EPI>
__global__ __launch_bounds__(256) void k_gemm(const bf16* __restrict__ A,
        const bf16* __restrict__ BT, const float* __restrict__ bias,
        const float* __restrict__ resid, float* __restrict__ outF,
        bf16* __restrict__ outB, int M, int N, int K) {
    __shared__ __align__(16) bf16 As[128 * 64];
    __shared__ __align__(16) bf16 Bs[128 * 64];
    const int tid = threadIdx.x;
    const int lane = tid & 63, wave = tid >> 6;
    const int wm = wave >> 1, wn = wave & 1;     // 2x2 waves, 64x64 each
    const int lr = lane & 15, lk = lane >> 4;
    const int bn = blockIdx.x, bm = blockIdx.y;

    f32x4 acc[4][4] = {};

    const int64_t aBase = (int64_t)bm * 128 * K;
    const int64_t bBase = (int64_t)bn * 128 * K;

    for (int kt = 0; kt < K; kt += 64) {
        __syncthreads();
        #pragma unroll
        for (int i = 0; i < 4; i++) {
            int q = i * 256 + tid;      // 0..1023 chunk id
            int r = q >> 3, c8 = q & 7; // row, 16B-chunk within row
            GLOAD16(A  + aBase + (int64_t)r * K + kt + c8 * 8, As + q * 8);
            GLOAD16(BT + bBase + (int64_t)r * K + kt + c8 * 8, Bs + q * 8);
        }
        __syncthreads();   // compiler drains vmcnt before s_barrier (m97 pattern)
        #pragma unroll
        for (int kk = 0; kk < 2; kk++) {
            short8 af[4], bf_[4];
            #pragma unroll
            for (int f = 0; f < 4; f++) {
                af[f]  = *(const short8*)(As + (wm * 64 + f * 16 + lr) * 64 + kk * 32 + lk * 8);
                bf_[f] = *(const short8*)(Bs + (wn * 64 + f * 16 + lr) * 64 + kk * 32 + lk * 8);
            }
            #pragma unroll
            for (int fm = 0; fm < 4; fm++)
                #pragma unroll
                for (int fn = 0; fn < 4; fn++)
                    acc[fm][fn] = __builtin_amdgcn_mfma_f32_16x16x32_bf16(
                        af[fm], bf_[fn], acc[fm][fn], 0, 0, 0);
        }
    }

    #pragma unroll
    for (int fm = 0; fm < 4; fm++) {
        #pragma unroll
        for (int fn = 0; fn < 4; fn++) {
            const int col = bn * 128 + wn * 64 + fn * 16 + lr;
            #pragma unroll
            for (int r = 0; r < 4; r++) {
                const int row = bm * 128 + wm * 64 + fm * 16 + lk * 4 + r;
                float v = acc[fm][fn][r];
                if constexpr (EPI & 1) v += bias[col];
                if constexpr (EPI & 2) v = fmaxf(v, 0.f);
                if constexpr (EPI & 4) v += resid[(int64_t)row * N + col];
                if constexpr (EPI & 8) outF[(int64_t)row * N + col] = v;
                else outB[(int64_t)row * N + col] = __float2bfloat16(v);
            }
        }
    }
}

// ---------------- MFMA flash attention, balanced 2-tile waves ----------------
// Each wave owns q-tiles {qp, 63-qp}: constant total work, K/V loads shared
// over the common prefix. S^T = mfma(K,Q): col=query(lane&15), row=key.
// ctx^T = mfma(V^T, P^T): col=query, row=dim. m/l state lane-local per query.
__device__ __forceinline__ void attn_tile(int k0, int qg, int nk,
        short8 qf0, short8 qf1,
        short8 kf00, short8 kf01, short8 kf10, short8 kf11,
        const short8* vf, f32x4 (&ctx)[4], float& mrun, float& lrun,
        int c, int g, float scale) {
    f32x4 st0 = {}, st1 = {};
    st0 = __builtin_amdgcn_mfma_f32_16x16x32_bf16(kf00, qf0, st0, 0, 0, 0);
    st0 = __builtin_amdgcn_mfma_f32_16x16x32_bf16(kf01, qf1, st0, 0, 0, 0);
    const bool h2 = (k0 + 16 < nk);
    if (h2) {
        st1 = __builtin_amdgcn_mfma_f32_16x16x32_bf16(kf10, qf0, st1, 0, 0, 0);
        st1 = __builtin_amdgcn_mfma_f32_16x16x32_bf16(kf11, qf1, st1, 0, 0, 0);
    }
    float sv[8];
    #pragma unroll
    for (int r = 0; r < 4; r++) {
        int kg = k0 + 4 * g + r;
        sv[r] = (kg <= qg) ? st0[r] * scale : -INFINITY;
    }
    #pragma unroll
    for (int r = 0; r < 4; r++) {
        int kg = k0 + 16 + 4 * g + r;
        sv[4 + r] = (h2 && kg <= qg) ? st1[r] * scale : -INFINITY;
    }
    float bm = sv[0];
    #pragma unroll
    for (int i = 1; i < 8; i++) bm = fmaxf(bm, sv[i]);
    bm = fmaxf(bm, __shfl_xor(bm, 16));
    bm = fmaxf(bm, __shfl_xor(bm, 32));
    const float mnew = fmaxf(mrun, bm);
    float p[8], psum = 0.f;
    #pragma unroll
    for (int i = 0; i < 8; i++) { p[i] = __expf(sv[i] - mnew); psum += p[i]; }
    psum += __shfl_xor(psum, 16);
    psum += __shfl_xor(psum, 32);
    const float facc = __expf(mrun - mnew);   // 0 on first block (ctx=0)
    lrun = lrun * facc + psum;
    mrun = mnew;
    #pragma unroll
    for (int dt = 0; dt < 4; dt++) ctx[dt] *= facc;

    auto pk = [](float a, float b2) -> uint32_t {
        uint16_t lo = __hip_bfloat16_raw(__float2bfloat16(a)).x;
        uint16_t hi = __hip_bfloat16_raw(__float2bfloat16(b2)).x;
        return (uint32_t)lo | ((uint32_t)hi << 16);
    };
    uint32_t w00 = pk(p[0], p[1]), w01 = pk(p[2], p[3]);   // tile0 keys 4g+{0..3}
    uint32_t w10 = pk(p[4], p[5]), w11 = pk(p[6], p[7]);   // tile1
    const int srcA = c + ((g & 1) << 5);
    const int srcB = srcA + 16;
    uint32_t x0 = (uint32_t)__shfl((int)w00, srcA);
    uint32_t x1 = (uint32_t)__shfl((int)w01, srcA);
    uint32_t x2 = (uint32_t)__shfl((int)w00, srcB);
    uint32_t x3 = (uint32_t)__shfl((int)w01, srcB);
    uint32_t y0 = (uint32_t)__shfl((int)w10, srcA);
    uint32_t y1 = (uint32_t)__shfl((int)w11, srcA);
    uint32_t y2 = (uint32_t)__shfl((int)w10, srcB);
    uint32_t y3 = (uint32_t)__shfl((int)w11, srcB);
    union { uint32_t u[4]; short8 v; } pa;
    const bool hi2 = (g >= 2);
    pa.u[0] = hi2 ? y0 : x0; pa.u[1] = hi2 ? y1 : x1;
    pa.u[2] = hi2 ? y2 : x2; pa.u[3] = hi2 ? y3 : x3;

    #pragma unroll
    for (int dt = 0; dt < 4; dt++)
        ctx[dt] = __builtin_amdgcn_mfma_f32_16x16x32_bf16(vf[dt], pa.v, ctx[dt], 0, 0, 0);
}

__global__ __launch_bounds__(256) void k_attn3(const bf16* __restrict__ Q,
        const bf16* __restrict__ Kb, const bf16* __restrict__ Vt,
        bf16* __restrict__ O) {
    const int lane = threadIdx.x & 63;
    const int wave = threadIdx.x >> 6;
    int bid = (blockIdx.x & 7) * 128 + (blockIdx.x >> 3);  // XCD swizzle, bijective on 1024
    const int wid = bid * 4 + wave;                        // 0..4095
    const int qp = wid & 31, h = (wid >> 5) & 15, b = wid >> 9;
    const int q0A = qp * 16, q0B = (63 - qp) * 16;
    const int c = lane & 15, g = lane >> 4;
    const int qgA = q0A + c, qgB = q0B + c;
    const float scale = 1.0f / 32.0f;      // D^-0.5 (full embed dim, per ref)

    const bf16* qrowA = Q + ((int64_t)(b * TT + q0A + c)) * TD + h * 64 + g * 8;
    short8 qA0 = *(const short8*)(qrowA);
    short8 qA1 = *(const short8*)(qrowA + 32);
    const bf16* qrowB = Q + ((int64_t)(b * TT + q0B + c)) * TD + h * 64 + g * 8;
    short8 qB0 = *(const short8*)(qrowB);
    short8 qB1 = *(const short8*)(qrowB + 32);

    f32x4 ctxA[4] = {}, ctxB[4] = {};
    float mA = -INFINITY, lA = 0.f, mB = -INFINITY, lB = 0.f;

    const bf16* kbase = Kb + ((int64_t)b * TT) * TD + h * 64;
    const bf16* vbase = Vt + ((int64_t)(b * TH + h) * 64) * TT;

    const int nkA = q0A + 16, nkB = q0B + 16;
    for (int k0 = 0; k0 < nkB; k0 += 32) {
        const bf16* kp = kbase + (int64_t)(k0 + c) * TD + g * 8;
        short8 kf00 = *(const short8*)(kp);
        short8 kf01 = *(const short8*)(kp + 32);
        short8 kf10 = {}, kf11 = {};
        if (k0 + 16 < nkB) {
            kf10 = *(const short8*)(kp + 16 * TD);
            kf11 = *(const short8*)(kp + 16 * TD + 32);
        }
        short8 vf[4];
        #pragma unroll
        for (int dt = 0; dt < 4; dt++)
            vf[dt] = *(const short8*)(vbase + (int64_t)(dt * 16 + c) * TT + k0 + g * 8);

        attn_tile(k0, qgB, nkB, qB0, qB1, kf00, kf01, kf10, kf11, vf,
                  ctxB, mB, lB, c, g, scale);
        if (k0 < nkA)
            attn_tile(k0, qgA, nkA, qA0, qA1, kf00, kf01, kf10, kf11, vf,
                      ctxA, mA, lA, c, g, scale);
    }

    // ---- epilogue: O[token q0+c][h*64 + dim], dim = dt*16 + 4g + r ----
    const float invA = 1.0f / lA, invB = 1.0f / lB;
    bf16* orowA = O + ((int64_t)(b * TT + q0A + c)) * TD + h * 64 + g * 4;
    bf16* orowB = O + ((int64_t)(b * TT + q0B + c)) * TD + h * 64 + g * 4;
    #pragma unroll
    for (int dt = 0; dt < 4; dt++) {
        bf16 t4[4];
        #pragma unroll
        for (int r = 0; r < 4; r++) t4[r] = __float2bfloat16(ctxA[dt][r] * invA);
        *(uint2*)(orowA + dt * 16) = *(uint2*)t4;
        #pragma unroll
        for (int r = 0; r < 4; r++) t4[r] = __float2bfloat16(ctxB[dt][r] * invB);
        *(uint2*)(orowB + dt * 16) = *(uint2*)t4;
    }
}

extern "C" void kernel_launch(void* const* d_in, const int* in_sizes, int n_in,
                              void* d_out, int out_size, void* d_ws, size_t ws_size,
                              hipStream_t stream) {
    const int*   idx  = (const int*)  d_in[0];
    const float* tok  = (const float*)d_in[1];
    const float* pos  = (const float*)d_in[2];
    const float* wq   = (const float*)d_in[3];
    const float* wk   = (const float*)d_in[4];
    const float* wv   = (const float*)d_in[5];
    const float* wp   = (const float*)d_in[6];
    const float* bp   = (const float*)d_in[7];
    const float* ln1w = (const float*)d_in[8];
    const float* ln1b = (const float*)d_in[9];
    const float* ln2w = (const float*)d_in[10];
    const float* ln2b = (const float*)d_in[11];
    const float* w1   = (const float*)d_in[12];
    const float* b1   = (const float*)d_in[13];
    const float* w2   = (const float*)d_in[14];
    const float* b2   = (const float*)d_in[15];
    float* x = (float*)d_out;   // residual stream lives in d_out (fp32)

    char* ws = (char*)d_ws;
    size_t off = 0;
    auto alloc = [&](size_t bytes) {
        char* p = ws + off; off += (bytes + 255) & ~(size_t)255; return p;
    };
    bf16* h   = (bf16*)alloc((size_t)TM * TD * 2);
    bf16* qb  = (bf16*)alloc((size_t)TM * TD * 2);
    bf16* kb  = (bf16*)alloc((size_t)TM * TD * 2);
    bf16* vb  = (bf16*)alloc((size_t)TM * TD * 2);
    bf16* ctx = (bf16*)alloc((size_t)TM * TD * 2);
    bf16* ffa = (bf16*)alloc((size_t)TM * TDF * 2);
    bf16* wqT = (bf16*)alloc((size_t)TD * TD * 2);
    bf16* wkT = (bf16*)alloc((size_t)TD * TD * 2);
    bf16* wvT = (bf16*)alloc((size_t)TD * TD * 2);
    bf16* wpT = (bf16*)alloc((size_t)TD * TD * 2);
    bf16* w1T = (bf16*)alloc((size_t)TD * TDF * 2);
    bf16* w2T = (bf16*)alloc((size_t)TD * TDF * 2);
    bf16* vt  = (bf16*)ffa;   // reuse: ffa is dead during attention

    k_embed<<<TM, 256, 0, stream>>>(idx, tok, pos, x);

    const dim3 gD(TD / 128, TM / 128);    // (8, 64)
    const dim3 gF1(TDF / 128, TM / 128);  // (32, 64)

    for (int l = 0; l < TL; l++) {
        k_transpose<<<dim3(TD / 64, TD / 64), 256, 0, stream>>>(wq + (int64_t)l * TD * TD, wqT, TD, TD);
        k_transpose<<<dim3(TD / 64, TD / 64), 256, 0, stream>>>(wk + (int64_t)l * TD * TD, wkT, TD, TD);
        k_transpose<<<dim3(TD / 64, TD / 64), 256, 0, stream>>>(wv + (int64_t)l * TD * TD, wvT, TD, TD);
        k_transpose<<<dim3(TD / 64, TD / 64), 256, 0, stream>>>(wp + (int64_t)l * TD * TD, wpT, TD, TD);
        k_transpose<<<dim3(TDF / 64, TD / 64), 256, 0, stream>>>(w1 + (int64_t)l * TD * TDF, w1T, TD, TDF);
        k_transpose<<<dim3(TD / 64, TDF / 64), 256, 0, stream>>>(w2 + (int64_t)l * TDF * TD, w2T, TDF, TD);

        k_ln<<<TM, 256, 0, stream>>>(x, ln1w + l * TD, ln1b + l * TD, h);
        k_gemm<0><<<gD, 256, 0, stream>>>(h, wqT, nullptr, nullptr, nullptr, qb, TM, TD, TD);
        k_gemm<0><<<gD, 256, 0, stream>>>(h, wkT, nullptr, nullptr, nullptr, kb, TM, TD, TD);
        k_gemm<0><<<gD, 256, 0, stream>>>(h, wvT, nullptr, nullptr, nullptr, vb, TM, TD, TD);
        k_vt<<<dim3(TB * TH, TT / 64), 256, 0, stream>>>(vb, vt);
        k_attn3<<<TB * TH * 32 / 4, 256, 0, stream>>>(qb, kb, vt, ctx);
        k_gemm<13><<<gD, 256, 0, stream>>>(ctx, wpT, bp + l * TD, x, x, nullptr, TM, TD, TD);
        k_ln<<<TM, 256, 0, stream>>>(x, ln2w + l * TD, ln2b + l * TD, h);
        k_gemm<3><<<gF1, 256, 0, stream>>>(h, w1T, b1 + l * TDF, nullptr, nullptr, ffa, TM, TDF, TD);
        k_gemm<13><<<gD, 256, 0, stream>>>(ffa, w2T, b2 + l * TD, x, x, nullptr, TM, TD, TDF);
    }
    (void)in_sizes; (void)n_in; (void)out_size; (void)ws_size;
}